// Round 12
// baseline (591.600 us; speedup 1.0000x reference)
//
#include <hip/hip_runtime.h>
#include <math.h>

#define N_STEPS 50
#define DT 0.02f

typedef __attribute__((ext_vector_type(8))) short    bf16x8;
typedef __attribute__((ext_vector_type(4))) float    f32x4;
typedef __attribute__((ext_vector_type(4))) unsigned u32x4;

// RNE float->bf16 (software, setup-time only)
__device__ inline unsigned f2bf(float f) {
    unsigned u = __builtin_bit_cast(unsigned, f);
    return ((u + 0x7FFFu + ((u >> 16) & 1u)) >> 16);
}
__device__ inline unsigned pk2(float lo, float hi) {
    return (f2bf(lo) & 0xFFFFu) | (f2bf(hi) << 16);
}
// fast per-step packed convert (1 instr)
__device__ inline unsigned cvtpk(float lo, float hi) {
    unsigned r;
    asm("v_cvt_pk_bf16_f32 %0, %1, %2" : "=v"(r) : "v"(lo), "v"(hi));
    return r;
}
__device__ inline bf16x8 mk8(unsigned a, unsigned b, unsigned cc, unsigned d) {
    u32x4 t; t.x = a; t.y = b; t.z = cc; t.w = d;
    return __builtin_bit_cast(bf16x8, t);
}
// tanh(x) = 1 - 2/(2^(x*2*log2 e) + 1); v_exp_f32 + v_rcp_f32.
__device__ inline float fast_tanh(float x) {
    float e, r;
    asm("v_exp_f32 %0, %1" : "=v"(e) : "v"(x * 2.8853900817779268f));
    asm("v_rcp_f32 %0, %1" : "=v"(r) : "v"(e + 1.0f));
    return fmaf(-2.0f, r, 1.0f);
}

// sum pv[t4] over lane-groups (xor 16, 32), then select this lane's tile.
__device__ inline float red4(const float pv[4], int g) {
    float r4[4];
#pragma unroll
    for (int t4 = 0; t4 < 4; ++t4) {
        float v = pv[t4];
        v += __shfl_xor(v, 16, 64);
        v += __shfl_xor(v, 32, 64);
        r4[t4] = v;
    }
    float pick = r4[0];
    pick = (g == 1) ? r4[1] : pick;
    pick = (g == 2) ? r4[2] : pick;
    pick = (g == 3) ? r4[3] : pick;
    return pick;
}

// Block = 64 threads = ONE wave handling BOTH nets for 64 paths (round 11).
//
// Round-12 change vs round 11: occupancy is GRID-limited at 2 waves/SIMD
// (2048 waves / 1024 SIMDs), so VGPRs up to the 256 cap are free. Spend
// them to delete redundant LDS traffic in the hot loop:
//   - L2 restructured t4-outer with the 4 distinct hf fragments hoisted
//     per t4 (16 ds_read_b128/step instead of 64 -- round 11 re-read each
//     fragment 4x under mt-outer) plus their address/XOR VALU and waitcnts.
//   - W3 back in registers (16 x f32x4; round 9 evicted it when the VGPR
//     cap was 128 and spilling -- no longer binding).
//   - w3c LDS table and setup barrier deleted.
// Per-output accumulation order over (mt,r) is unchanged -> bitwise
// identical output (absmax stays 0.001953125).
// Tripwire: WRITE_SIZE must stay ~1.6 MB; a jump = cap overflow spill.
__global__ __launch_bounds__(64, 2) void bsde_kernel(
    const float* __restrict__ y0v, const float* __restrict__ Y0v,
    const float* __restrict__ qW1, const float* __restrict__ qb1,
    const float* __restrict__ qW2, const float* __restrict__ qb2,
    const float* __restrict__ qW3, const float* __restrict__ qb3,
    const float* __restrict__ zW1, const float* __restrict__ zb1,
    const float* __restrict__ zW2, const float* __restrict__ zb2,
    const float* __restrict__ zW3, const float* __restrict__ zb3,
    const float* __restrict__ dW,
    float* __restrict__ out, int B)
{
    const int lane = threadIdx.x;             // 0..63
    const int c    = lane & 15;               // path-col within a 16-tile
    const int g    = lane >> 4;               // lane group
    const int p    = blockIdx.x * 64 + lane;  // this lane's path

    __shared__ unsigned short ex[64 * 128];   // 16KB: [path][net*64 + h1] bf16

    // ---------------- one-time weight fragment preload ----------------
    // mt 0..3 = z-net, mt 4..7 = q-net; h = 16*(mt&3)+c within the net.
    bf16x8 w1f[8];
#pragma unroll
    for (int mt = 0; mt < 8; ++mt) {
        const float* W1 = (mt < 4) ? zW1 : qW1;
        const float* b1 = (mt < 4) ? zb1 : qb1;
        const int h = 16 * (mt & 3) + c;
        unsigned d0 = 0, d1 = 0, d2 = 0;
        if (g == 0) {
            d0 = pk2(W1[0 * 64 + h], W1[1 * 64 + h]);   // k0=t, k1=y0
            d1 = pk2(W1[2 * 64 + h], W1[3 * 64 + h]);   // k2=y1, k3=y2
            d2 = f2bf(b1[h]) & 0xFFFFu;                 // k4=1-const row
        }
        w1f[mt] = mk8(d0, d1, d2, 0);
    }

    bf16x8 w2f[8][2];
#pragma unroll
    for (int mt = 0; mt < 8; ++mt) {
        const float* W2 = (mt < 4) ? zW2 : qW2;
        const int h = 16 * (mt & 3) + c;
#pragma unroll
        for (int kt = 0; kt < 2; ++kt) {
            const int k0 = 32 * kt + 8 * g;
            w2f[mt][kt] = mk8(
                pk2(W2[(k0 + 0) * 64 + h], W2[(k0 + 1) * 64 + h]),
                pk2(W2[(k0 + 2) * 64 + h], W2[(k0 + 3) * 64 + h]),
                pk2(W2[(k0 + 4) * 64 + h], W2[(k0 + 5) * 64 + h]),
                pk2(W2[(k0 + 6) * 64 + h], W2[(k0 + 7) * 64 + h]));
        }
    }

    f32x4 b2v[8];
#pragma unroll
    for (int mt = 0; mt < 8; ++mt) {
        const float* b2 = (mt < 4) ? zb2 : qb2;
#pragma unroll
        for (int r = 0; r < 4; ++r)
            b2v[mt][r] = b2[16 * (mt & 3) + 4 * g + r];
    }

    // W3 in registers, C-layout per lane (grid-limited occupancy -> free).
    f32x4 w3z0[4], w3z1[4], w3z2[4], w3q[4];
#pragma unroll
    for (int mt = 0; mt < 4; ++mt)
#pragma unroll
    for (int r = 0; r < 4; ++r) {
        const int h = 16 * mt + 4 * g + r;
        w3z0[mt][r] = zW3[3 * h + 0];
        w3z1[mt][r] = zW3[3 * h + 1];
        w3z2[mt][r] = zW3[3 * h + 2];
        w3q[mt][r]  = qW3[h];
    }

    const float zb3_0 = zb3[0], zb3_1 = zb3[1], zb3_2 = zb3[2];
    const float qb3_0 = qb3[0];

    char* exn = (char*)ex;
    const int sw = (c & 7) << 4;              // LDS XOR swizzle key (bits 4-6)
    const unsigned jp2c = (g == 0) ? 0x3F80u : 0u;   // bf16(1.0) in k=4 slot

    const float sqrt_dt = sqrtf(DT);
    float y0 = y0v[0], y1 = y0v[1], y2 = y0v[2];
    float Y  = Y0v[0];

    for (int n = 0; n < N_STEPS; ++n) {
        const float t = (float)n * DT;

        const size_t idx = ((size_t)n * (size_t)B + (size_t)p) * 3;
        const float dr0 = dW[idx + 0];
        const float dr1 = dW[idx + 1];
        const float dr2 = dW[idx + 2];

        // ---- L1: shared xf per t4, 8 MFMA (both nets), relu+pack+write ----
#pragma unroll
        for (int t4 = 0; t4 < 4; ++t4) {
            const int src = 16 * t4 + c;
            const float s0 = __shfl(y0, src, 64);
            const float s1 = __shfl(y1, src, 64);
            const float s2 = __shfl(y2, src, 64);
            const unsigned a = cvtpk(t,  s0);
            const unsigned b = cvtpk(s1, s2);
            const bf16x8 xf = mk8((g == 0) ? a : 0u, (g == 0) ? b : 0u, jp2c, 0u);
#pragma unroll
            for (int mt = 0; mt < 8; ++mt) {
                f32x4 c1 = __builtin_amdgcn_mfma_f32_16x16x32_bf16(
                    w1f[mt], xf, (f32x4){0.f, 0.f, 0.f, 0.f}, 0, 0, 0);
                const unsigned lo = cvtpk(fmaxf(c1[0], 0.f), fmaxf(c1[1], 0.f));
                const unsigned hi = cvtpk(fmaxf(c1[2], 0.f), fmaxf(c1[3], 0.f));
                const int off = (((16 * t4 + c) * 256) + (mt >> 2) * 128
                                 + 32 * (mt & 3) + 8 * g) ^ sw;
                *(unsigned long long*)(exn + off) =
                    ((unsigned long long)hi << 32) | (unsigned long long)lo;
            }
        }

        // ---- L2 + L3 partials, t4-outer: 4 distinct hf frags hoisted ----
        float pz0[4] = {0.f, 0.f, 0.f, 0.f};
        float pz1[4] = {0.f, 0.f, 0.f, 0.f};
        float pz2[4] = {0.f, 0.f, 0.f, 0.f};
        float pq [4] = {0.f, 0.f, 0.f, 0.f};
#pragma unroll
        for (int t4 = 0; t4 < 4; ++t4) {
            const int rb = ((16 * t4 + c) * 256) + 16 * g;
            const bf16x8 hz0 = *(const bf16x8*)(exn + ((rb +   0) ^ sw));
            const bf16x8 hz1 = *(const bf16x8*)(exn + ((rb +  64) ^ sw));
            const bf16x8 hq0 = *(const bf16x8*)(exn + ((rb + 128) ^ sw));
            const bf16x8 hq1 = *(const bf16x8*)(exn + ((rb + 192) ^ sw));
#pragma unroll
            for (int mt = 0; mt < 8; ++mt) {
                const bf16x8 h0 = (mt < 4) ? hz0 : hq0;
                const bf16x8 h1 = (mt < 4) ? hz1 : hq1;
                f32x4 acc = __builtin_amdgcn_mfma_f32_16x16x32_bf16(
                    w2f[mt][0], h0, b2v[mt], 0, 0, 0);
                acc = __builtin_amdgcn_mfma_f32_16x16x32_bf16(
                    w2f[mt][1], h1, acc, 0, 0, 0);
#pragma unroll
                for (int r = 0; r < 4; ++r) {
                    const float h = fmaxf(acc[r], 0.f);
                    if (mt < 4) {
                        pz0[t4] = fmaf(h, w3z0[mt][r], pz0[t4]);
                        pz1[t4] = fmaf(h, w3z1[mt][r], pz1[t4]);
                        pz2[t4] = fmaf(h, w3z2[mt][r], pz2[t4]);
                    } else {
                        pq[t4]  = fmaf(h, w3q[mt - 4][r], pq[t4]);
                    }
                }
            }
        }

        // ---- cross-lane reduce: land each path's 4 outputs on its lane ----
        const float oz0 = red4(pz0, g) + zb3_0;
        const float oz1 = red4(pz1, g) + zb3_1;
        const float oz2 = red4(pz2, g) + zb3_2;
        const float qq  = red4(pq,  g) + qb3_0;

        // ---- SDE update (same expression order as rounds 0-11) ----
        const float dw0 = dr0 * sqrt_dt;
        const float dw1 = dr1 * sqrt_dt;
        const float dw2 = dr2 * sqrt_dt;

        const float f = 0.5f * qq * qq;
        Y = Y - f * DT + (oz0 * dw0 + oz1 * dw1 + oz2 * dw2);

        const float s0 = 0.2f + 0.1f * fast_tanh(y0);
        const float s1 = 0.2f + 0.1f * fast_tanh(y1);
        const float s2 = 0.2f + 0.1f * fast_tanh(y2);
        y0 = y0 + (qq - y0) * DT + s0 * dw0;
        y1 = y1 + (qq - y1) * DT + s1 * dw1;
        y2 = y2 + (qq - y2) * DT + s2 * dw2;
    }

    const float term = y0 * y0 + y1 * y1 + y2 * y2;
    const float d    = Y - term;
    float val = d * d;
#pragma unroll
    for (int off = 32; off > 0; off >>= 1)
        val += __shfl_down(val, off, 64);
    if (lane == 0)
        atomicAdd(out, val * (1.0f / (float)B));
}

extern "C" void kernel_launch(void* const* d_in, const int* in_sizes, int n_in,
                              void* d_out, int out_size, void* d_ws, size_t ws_size,
                              hipStream_t stream) {
    const float* y0  = (const float*)d_in[0];
    const float* Y0  = (const float*)d_in[1];
    const float* qW1 = (const float*)d_in[2];
    const float* qb1 = (const float*)d_in[3];
    const float* qW2 = (const float*)d_in[4];
    const float* qb2 = (const float*)d_in[5];
    const float* qW3 = (const float*)d_in[6];
    const float* qb3 = (const float*)d_in[7];
    const float* zW1 = (const float*)d_in[8];
    const float* zb1 = (const float*)d_in[9];
    const float* zW2 = (const float*)d_in[10];
    const float* zb2 = (const float*)d_in[11];
    const float* zW3 = (const float*)d_in[12];
    const float* zb3 = (const float*)d_in[13];
    const float* dW  = (const float*)d_in[14];

    const int B = in_sizes[14] / (N_STEPS * 3);   // 131072
    float* out = (float*)d_out;

    hipMemsetAsync(out, 0, sizeof(float), stream);

    const int threads = 64;                        // 1 wave, both nets
    const int blocks  = B / 64;                    // 2048 independent waves
    bsde_kernel<<<blocks, threads, 0, stream>>>(
        y0, Y0, qW1, qb1, qW2, qb2, qW3, qb3,
        zW1, zb1, zW2, zb2, zW3, zb3, dW, out, B);
}

// Round 13
// 446.752 us; speedup vs baseline: 1.3242x; 1.3242x over previous
//
#include <hip/hip_runtime.h>
#include <math.h>

#define N_STEPS 50
#define DT 0.02f

typedef __attribute__((ext_vector_type(8))) short    bf16x8;
typedef __attribute__((ext_vector_type(4))) float    f32x4;
typedef __attribute__((ext_vector_type(4))) unsigned u32x4;

// RNE float->bf16 (software, setup-time only)
__device__ inline unsigned f2bf(float f) {
    unsigned u = __builtin_bit_cast(unsigned, f);
    return ((u + 0x7FFFu + ((u >> 16) & 1u)) >> 16);
}
__device__ inline unsigned pk2(float lo, float hi) {
    return (f2bf(lo) & 0xFFFFu) | (f2bf(hi) << 16);
}
// fast per-step packed convert (1 instr)
__device__ inline unsigned cvtpk(float lo, float hi) {
    unsigned r;
    asm("v_cvt_pk_bf16_f32 %0, %1, %2" : "=v"(r) : "v"(lo), "v"(hi));
    return r;
}
__device__ inline bf16x8 mk8(unsigned a, unsigned b, unsigned cc, unsigned d) {
    u32x4 t; t.x = a; t.y = b; t.z = cc; t.w = d;
    return __builtin_bit_cast(bf16x8, t);
}
// tanh(x) = 1 - 2/(2^(x*2*log2 e) + 1); v_exp_f32 + v_rcp_f32.
__device__ inline float fast_tanh(float x) {
    float e, r;
    asm("v_exp_f32 %0, %1" : "=v"(e) : "v"(x * 2.8853900817779268f));
    asm("v_rcp_f32 %0, %1" : "=v"(r) : "v"(e + 1.0f));
    return fmaf(-2.0f, r, 1.0f);
}

// Block = 64 threads = ONE wave handling BOTH nets for 64 paths.
//
// Round-13 change vs rounds 11/12: round 12 proved the arch-VGPR budget is
// ~128 and that extra state survives ONLY if it is MFMA-operand-only
// (AGPR-eligible); VALU-read arrays spill. So the fp32 output layer
// (256 fma + 128 fmax partials + 32 ds_swizzle reduce + w3 reads -- the
// largest VALU block) is replaced by a THIRD MFMA stage:
//   out[4 x 16] = W3blk[4 x 128] x relu(h2)[128 x 16]  per path-tile,
// with W3blk block-diagonal (rows 0..2 = zW3 over k<64, row 3 = qW3 over
// k>=64) and biases injected via the C operand. w3f is an A-operand ->
// AGPR -> zero arch pressure. L2 is now t4-outer with the 4 h1 fragments
// hoisted, and relu(h2) is packed to bf16 and written back into the SAME
// ex rows (in-wave DS ordering makes the overwrite safe), so LDS stays
// 16 KB. Outputs land in C layout; 16 shfl + 12 selects deliver each
// path's (z0,z1,z2,q) to its owner lane.
// NOTE: L3 now computes in bf16 (arithmetic change; absmax expected to
// rise from 1.95e-3 toward ~3-5e-3, threshold 7.7e-3).
__global__ __launch_bounds__(64, 2) void bsde_kernel(
    const float* __restrict__ y0v, const float* __restrict__ Y0v,
    const float* __restrict__ qW1, const float* __restrict__ qb1,
    const float* __restrict__ qW2, const float* __restrict__ qb2,
    const float* __restrict__ qW3, const float* __restrict__ qb3,
    const float* __restrict__ zW1, const float* __restrict__ zb1,
    const float* __restrict__ zW2, const float* __restrict__ zb2,
    const float* __restrict__ zW3, const float* __restrict__ zb3,
    const float* __restrict__ dW,
    float* __restrict__ out, int B)
{
    const int lane = threadIdx.x;             // 0..63
    const int c    = lane & 15;               // path-col within a 16-tile
    const int g    = lane >> 4;               // lane group
    const int p    = blockIdx.x * 64 + lane;  // this lane's path

    __shared__ unsigned short ex[64 * 128];   // 16KB: [path][net*64 + idx] bf16

    // ---------------- one-time weight fragment preload ----------------
    // mt 0..3 = z-net, mt 4..7 = q-net; h = 16*(mt&3)+c within the net.
    bf16x8 w1f[8];
#pragma unroll
    for (int mt = 0; mt < 8; ++mt) {
        const float* W1 = (mt < 4) ? zW1 : qW1;
        const float* b1 = (mt < 4) ? zb1 : qb1;
        const int h = 16 * (mt & 3) + c;
        unsigned d0 = 0, d1 = 0, d2 = 0;
        if (g == 0) {
            d0 = pk2(W1[0 * 64 + h], W1[1 * 64 + h]);   // k0=t, k1=y0
            d1 = pk2(W1[2 * 64 + h], W1[3 * 64 + h]);   // k2=y1, k3=y2
            d2 = f2bf(b1[h]) & 0xFFFFu;                 // k4=1-const row
        }
        w1f[mt] = mk8(d0, d1, d2, 0);
    }

    bf16x8 w2f[8][2];
#pragma unroll
    for (int mt = 0; mt < 8; ++mt) {
        const float* W2 = (mt < 4) ? zW2 : qW2;
        const int h = 16 * (mt & 3) + c;
#pragma unroll
        for (int kt = 0; kt < 2; ++kt) {
            const int k0 = 32 * kt + 8 * g;
            w2f[mt][kt] = mk8(
                pk2(W2[(k0 + 0) * 64 + h], W2[(k0 + 1) * 64 + h]),
                pk2(W2[(k0 + 2) * 64 + h], W2[(k0 + 3) * 64 + h]),
                pk2(W2[(k0 + 4) * 64 + h], W2[(k0 + 5) * 64 + h]),
                pk2(W2[(k0 + 6) * 64 + h], W2[(k0 + 7) * 64 + h]));
        }
    }

    f32x4 b2v[8];
#pragma unroll
    for (int mt = 0; mt < 8; ++mt) {
        const float* b2 = (mt < 4) ? zb2 : qb2;
#pragma unroll
        for (int r = 0; r < 4; ++r)
            b2v[mt][r] = b2[16 * (mt & 3) + 4 * g + r];
    }

    // Stage-3 A-fragments: W3blk[4 x 128], block-diagonal.
    //   m(=c) 0..2: k<64 -> zW3[k*3+m];  m==3: k>=64 -> qW3[k-64]; else 0.
    bf16x8 w3f[4];
#pragma unroll
    for (int kt = 0; kt < 4; ++kt) {
        unsigned d[4];
#pragma unroll
        for (int jj = 0; jj < 4; ++jj) {
            const int k0 = 32 * kt + 8 * g + 2 * jj;
            float v[2];
#pragma unroll
            for (int e = 0; e < 2; ++e) {
                const int k = k0 + e;
                float val = 0.f;
                if (c < 3 && k < 64)        val = zW3[k * 3 + c];
                else if (c == 3 && k >= 64) val = qW3[k - 64];
                v[e] = val;
            }
            d[jj] = pk2(v[0], v[1]);
        }
        w3f[kt] = mk8(d[0], d[1], d[2], d[3]);
    }

    // Stage-3 C init: biases in C layout (rows 0..3 on g==0 lanes).
    const f32x4 c3i = { (g == 0) ? zb3[0] : 0.f,
                        (g == 0) ? zb3[1] : 0.f,
                        (g == 0) ? zb3[2] : 0.f,
                        (g == 0) ? qb3[0] : 0.f };

    char* exn = (char*)ex;
    const int sw = (c & 7) << 4;              // LDS XOR swizzle key (bits 4-6)
    const unsigned jp2c = (g == 0) ? 0x3F80u : 0u;   // bf16(1.0) in k=4 slot

    const float sqrt_dt = sqrtf(DT);
    float y0 = y0v[0], y1 = y0v[1], y2 = y0v[2];
    float Y  = Y0v[0];

    for (int n = 0; n < N_STEPS; ++n) {
        const float t = (float)n * DT;

        const size_t idx = ((size_t)n * (size_t)B + (size_t)p) * 3;
        const float dr0 = dW[idx + 0];
        const float dr1 = dW[idx + 1];
        const float dr2 = dW[idx + 2];

        // ---- L1: shared xf per t4, 8 MFMA (both nets), relu+pack+write ----
#pragma unroll
        for (int t4 = 0; t4 < 4; ++t4) {
            const int src = 16 * t4 + c;
            const float s0 = __shfl(y0, src, 64);
            const float s1 = __shfl(y1, src, 64);
            const float s2 = __shfl(y2, src, 64);
            const unsigned a = cvtpk(t,  s0);
            const unsigned b = cvtpk(s1, s2);
            const bf16x8 xf = mk8((g == 0) ? a : 0u, (g == 0) ? b : 0u, jp2c, 0u);
#pragma unroll
            for (int mt = 0; mt < 8; ++mt) {
                f32x4 c1 = __builtin_amdgcn_mfma_f32_16x16x32_bf16(
                    w1f[mt], xf, (f32x4){0.f, 0.f, 0.f, 0.f}, 0, 0, 0);
                const unsigned lo = cvtpk(fmaxf(c1[0], 0.f), fmaxf(c1[1], 0.f));
                const unsigned hi = cvtpk(fmaxf(c1[2], 0.f), fmaxf(c1[3], 0.f));
                const int off = (((16 * t4 + c) * 256) + (mt >> 2) * 128
                                 + 32 * (mt & 3) + 8 * g) ^ sw;
                *(unsigned long long*)(exn + off) =
                    ((unsigned long long)hi << 32) | (unsigned long long)lo;
            }
        }

        // ---- L2, t4-outer: read h1 frags, 16 MFMA, relu+pack h2 in-place ----
#pragma unroll
        for (int t4 = 0; t4 < 4; ++t4) {
            const int rb = ((16 * t4 + c) * 256) + 16 * g;
            const bf16x8 hz0 = *(const bf16x8*)(exn + ((rb +   0) ^ sw));
            const bf16x8 hz1 = *(const bf16x8*)(exn + ((rb +  64) ^ sw));
            const bf16x8 hq0 = *(const bf16x8*)(exn + ((rb + 128) ^ sw));
            const bf16x8 hq1 = *(const bf16x8*)(exn + ((rb + 192) ^ sw));
#pragma unroll
            for (int mt = 0; mt < 8; ++mt) {
                const bf16x8 h0 = (mt < 4) ? hz0 : hq0;
                const bf16x8 h1 = (mt < 4) ? hz1 : hq1;
                f32x4 acc = __builtin_amdgcn_mfma_f32_16x16x32_bf16(
                    w2f[mt][0], h0, b2v[mt], 0, 0, 0);
                acc = __builtin_amdgcn_mfma_f32_16x16x32_bf16(
                    w2f[mt][1], h1, acc, 0, 0, 0);
                const unsigned lo = cvtpk(fmaxf(acc[0], 0.f), fmaxf(acc[1], 0.f));
                const unsigned hi = cvtpk(fmaxf(acc[2], 0.f), fmaxf(acc[3], 0.f));
                const int off = (((16 * t4 + c) * 256) + (mt >> 2) * 128
                                 + 32 * (mt & 3) + 8 * g) ^ sw;
                *(unsigned long long*)(exn + off) =
                    ((unsigned long long)hi << 32) | (unsigned long long)lo;
            }
        }

        // ---- Stage 3: out[4x16] = W3blk x relu(h2), 4 MFMA per t4 ----
        f32x4 c3[4];
#pragma unroll
        for (int t4 = 0; t4 < 4; ++t4) {
            const int rb = ((16 * t4 + c) * 256) + 16 * g;
            f32x4 a3 = c3i;
#pragma unroll
            for (int kt = 0; kt < 4; ++kt) {
                const bf16x8 hf = *(const bf16x8*)(exn + ((rb + 64 * kt) ^ sw));
                a3 = __builtin_amdgcn_mfma_f32_16x16x32_bf16(w3f[kt], hf, a3, 0, 0, 0);
            }
            c3[t4] = a3;
        }

        // ---- distribute: path 16*t4+c reads row r from lane c of tile t4 ----
        float orv[4];
#pragma unroll
        for (int r = 0; r < 4; ++r) {
            const float v0 = __shfl(c3[0][r], c, 64);
            const float v1 = __shfl(c3[1][r], c, 64);
            const float v2 = __shfl(c3[2][r], c, 64);
            const float v3 = __shfl(c3[3][r], c, 64);
            float pick = v0;
            pick = (g == 1) ? v1 : pick;
            pick = (g == 2) ? v2 : pick;
            pick = (g == 3) ? v3 : pick;
            orv[r] = pick;
        }
        const float oz0 = orv[0];
        const float oz1 = orv[1];
        const float oz2 = orv[2];
        const float qq  = orv[3];

        // ---- SDE update (same expression order as rounds 0-12) ----
        const float dw0 = dr0 * sqrt_dt;
        const float dw1 = dr1 * sqrt_dt;
        const float dw2 = dr2 * sqrt_dt;

        const float f = 0.5f * qq * qq;
        Y = Y - f * DT + (oz0 * dw0 + oz1 * dw1 + oz2 * dw2);

        const float s0 = 0.2f + 0.1f * fast_tanh(y0);
        const float s1 = 0.2f + 0.1f * fast_tanh(y1);
        const float s2 = 0.2f + 0.1f * fast_tanh(y2);
        y0 = y0 + (qq - y0) * DT + s0 * dw0;
        y1 = y1 + (qq - y1) * DT + s1 * dw1;
        y2 = y2 + (qq - y2) * DT + s2 * dw2;
    }

    const float term = y0 * y0 + y1 * y1 + y2 * y2;
    const float d    = Y - term;
    float val = d * d;
#pragma unroll
    for (int off = 32; off > 0; off >>= 1)
        val += __shfl_down(val, off, 64);
    if (lane == 0)
        atomicAdd(out, val * (1.0f / (float)B));
}

extern "C" void kernel_launch(void* const* d_in, const int* in_sizes, int n_in,
                              void* d_out, int out_size, void* d_ws, size_t ws_size,
                              hipStream_t stream) {
    const float* y0  = (const float*)d_in[0];
    const float* Y0  = (const float*)d_in[1];
    const float* qW1 = (const float*)d_in[2];
    const float* qb1 = (const float*)d_in[3];
    const float* qW2 = (const float*)d_in[4];
    const float* qb2 = (const float*)d_in[5];
    const float* qW3 = (const float*)d_in[6];
    const float* qb3 = (const float*)d_in[7];
    const float* zW1 = (const float*)d_in[8];
    const float* zb1 = (const float*)d_in[9];
    const float* zW2 = (const float*)d_in[10];
    const float* zb2 = (const float*)d_in[11];
    const float* zW3 = (const float*)d_in[12];
    const float* zb3 = (const float*)d_in[13];
    const float* dW  = (const float*)d_in[14];

    const int B = in_sizes[14] / (N_STEPS * 3);   // 131072
    float* out = (float*)d_out;

    hipMemsetAsync(out, 0, sizeof(float), stream);

    const int threads = 64;                        // 1 wave, both nets
    const int blocks  = B / 64;                    // 2048 independent waves
    bsde_kernel<<<blocks, threads, 0, stream>>>(
        y0, Y0, qW1, qb1, qW2, qb2, qW3, qb3,
        zW1, zb1, zW2, zb2, zW3, zb3, dW, out, B);
}